// Round 1
// baseline (2705.886 us; speedup 1.0000x reference)
//
#include <hip/hip_runtime.h>
#include <hip/hip_bf16.h>

// Problem constants (B=4, S=4096 -> T=16384 tokens)
#define T_TOK 16384
#define H_DIM 1024
#define I_DIM 3584
#define E_NUM 8
#define TOTP  32768   // T_TOK * K(=2), exact total grouped positions

// GEMM tile config
#define BM 128
#define BN 128
#define BK 32
#define LDK 40        // padded LDS leading dim (bf16 elems); rows stay 16B-aligned (80B stride)

typedef __attribute__((ext_vector_type(8))) short s16x8;   // 8 bf16 (4 VGPRs) MFMA A/B frag
typedef __attribute__((ext_vector_type(4))) float f32x4;   // MFMA C/D frag

__device__ __forceinline__ unsigned short f2bf(float f) {
    union { float f; unsigned u; } c; c.f = f;
    unsigned r = c.u + 0x7fffu + ((c.u >> 16) & 1u);   // round-to-nearest-even
    return (unsigned short)(r >> 16);
}

// ---------------- Router: fp32 logits, top-2, renormalized weights ----------------
__global__ __launch_bounds__(64)
void router_k(const float* __restrict__ x, const float* __restrict__ gw,
              int* __restrict__ tk_idx, float* __restrict__ tk_w,
              int* __restrict__ counts)
{
    int t = blockIdx.x;
    int lane = threadIdx.x;
    const float* xr = x + (size_t)t * H_DIM;
    float xv[16];
#pragma unroll
    for (int j = 0; j < 16; j++) xv[j] = xr[j * 64 + lane];
    float lg[E_NUM];
#pragma unroll
    for (int e = 0; e < E_NUM; e++) {
        const float* g = gw + e * H_DIM;
        float s = 0.f;
#pragma unroll
        for (int j = 0; j < 16; j++) s += xv[j] * g[j * 64 + lane];
#pragma unroll
        for (int off = 32; off > 0; off >>= 1) s += __shfl_xor(s, off, 64);
        lg[e] = s;
    }
    if (lane == 0) {
        int i1 = 0; float m1 = lg[0];
#pragma unroll
        for (int e = 1; e < E_NUM; e++) if (lg[e] > m1) { m1 = lg[e]; i1 = e; }
        int i2 = -1; float m2 = -3.4e38f;
#pragma unroll
        for (int e = 0; e < E_NUM; e++) if (e != i1 && lg[e] > m2) { m2 = lg[e]; i2 = e; }
        // renormalized top-2 softmax weights: full-softmax denominator cancels
        float p1 = 1.f / (1.f + __expf(m2 - m1));
        float p2 = 1.f - p1;
        tk_idx[t * 2]     = i1;
        tk_idx[t * 2 + 1] = i2;
        tk_w[t * 2]       = p1;
        tk_w[t * 2 + 1]   = p2;
        atomicAdd(&counts[i1], 1);
        atomicAdd(&counts[i2], 1);
    }
}

// ---------------- Prefix sum over 8 counts ----------------
__global__ void offsets_k(const int* __restrict__ counts, int* __restrict__ offsets,
                          int* __restrict__ cursor)
{
    if (threadIdx.x == 0 && blockIdx.x == 0) {
        int acc = 0;
        for (int e = 0; e < E_NUM; e++) { offsets[e] = acc; cursor[e] = acc; acc += counts[e]; }
        offsets[E_NUM] = acc;
    }
}

// ---------------- Scatter token ids into per-expert groups ----------------
__global__ __launch_bounds__(256)
void scatter_k(const int* __restrict__ tk_idx, const float* __restrict__ tk_w,
               int* __restrict__ cursor, int* __restrict__ perm, float* __restrict__ pw)
{
    int t = blockIdx.x * 256 + threadIdx.x;
    if (t >= T_TOK) return;
#pragma unroll
    for (int k = 0; k < 2; k++) {
        int e = tk_idx[t * 2 + k];
        int pos = atomicAdd(&cursor[e], 1);
        perm[pos] = t;
        pw[pos]   = tk_w[t * 2 + k];
    }
}

// ---------------- GEMM1: hidden = silu(x@w1) * (x@w3), grouped by expert ----------------
// A: gathered x rows [cnt, H] fp32 -> bf16 at staging. B: w1/w3 [H, I] fp32 -> bf16.
// LDS tiles: As[m][k], B1s/B3s stored TRANSPOSED as [n][k] so frag reads are contiguous.
__global__ __launch_bounds__(256, 2)
void gemm1_k(const float* __restrict__ x, const float* __restrict__ w1,
             const float* __restrict__ w3, const int* __restrict__ offsets,
             const int* __restrict__ perm, unsigned short* __restrict__ hidden)
{
    int e = blockIdx.z;
    int base = offsets[e];
    int cnt  = offsets[e + 1] - base;
    int m0 = blockIdx.y * BM;
    if (m0 >= cnt) return;
    int n0 = blockIdx.x * BN;

    __shared__ unsigned short As[BM][LDK];
    __shared__ unsigned short B1s[BN][LDK];
    __shared__ unsigned short B3s[BN][LDK];

    int t = threadIdx.x;
    int lane = t & 63, wave = t >> 6;
    int wm = (wave >> 1) * 64, wn = (wave & 1) * 64;
    int l15 = lane & 15, quad = lane >> 4;

    int ar = t >> 1, ac = (t & 1) * 16;   // A staging: 2 threads/row x 16 elems
    int br = t >> 3, bc = (t & 7) * 16;   // B staging: 8 threads/row x 16 elems

    const float* xrow = nullptr;
    { int p = m0 + ar; if (p < cnt) xrow = x + (size_t)perm[base + p] * H_DIM; }

    const float* w1e = w1 + (size_t)e * H_DIM * I_DIM;
    const float* w3e = w3 + (size_t)e * H_DIM * I_DIM;

    f32x4 acc1[4][4] = {};
    f32x4 acc3[4][4] = {};

    for (int k0 = 0; k0 < H_DIM; k0 += BK) {
        // ---- stage A tile (fp32 -> bf16) ----
        {
            float4 a0, a1, a2, a3;
            if (xrow) {
                const float4* s = reinterpret_cast<const float4*>(xrow + k0 + ac);
                a0 = s[0]; a1 = s[1]; a2 = s[2]; a3 = s[3];
            } else {
                a0 = a1 = a2 = a3 = make_float4(0.f, 0.f, 0.f, 0.f);
            }
            unsigned short* d = &As[ar][ac];
            d[0] = f2bf(a0.x);  d[1] = f2bf(a0.y);  d[2] = f2bf(a0.z);  d[3] = f2bf(a0.w);
            d[4] = f2bf(a1.x);  d[5] = f2bf(a1.y);  d[6] = f2bf(a1.z);  d[7] = f2bf(a1.w);
            d[8] = f2bf(a2.x);  d[9] = f2bf(a2.y);  d[10] = f2bf(a2.z); d[11] = f2bf(a2.w);
            d[12] = f2bf(a3.x); d[13] = f2bf(a3.y); d[14] = f2bf(a3.z); d[15] = f2bf(a3.w);
        }
        // ---- stage B tiles (fp32 -> bf16, transposed into [n][k]) ----
        {
            size_t roff = (size_t)(k0 + br) * I_DIM + n0 + bc;
            const float4* s1 = reinterpret_cast<const float4*>(w1e + roff);
            const float4* s3 = reinterpret_cast<const float4*>(w3e + roff);
            float4 b0 = s1[0], b1 = s1[1], b2 = s1[2], b3 = s1[3];
            B1s[bc + 0][br]  = f2bf(b0.x);  B1s[bc + 1][br]  = f2bf(b0.y);
            B1s[bc + 2][br]  = f2bf(b0.z);  B1s[bc + 3][br]  = f2bf(b0.w);
            B1s[bc + 4][br]  = f2bf(b1.x);  B1s[bc + 5][br]  = f2bf(b1.y);
            B1s[bc + 6][br]  = f2bf(b1.z);  B1s[bc + 7][br]  = f2bf(b1.w);
            B1s[bc + 8][br]  = f2bf(b2.x);  B1s[bc + 9][br]  = f2bf(b2.y);
            B1s[bc + 10][br] = f2bf(b2.z);  B1s[bc + 11][br] = f2bf(b2.w);
            B1s[bc + 12][br] = f2bf(b3.x);  B1s[bc + 13][br] = f2bf(b3.y);
            B1s[bc + 14][br] = f2bf(b3.z);  B1s[bc + 15][br] = f2bf(b3.w);
            float4 c0 = s3[0], c1 = s3[1], c2 = s3[2], c3 = s3[3];
            B3s[bc + 0][br]  = f2bf(c0.x);  B3s[bc + 1][br]  = f2bf(c0.y);
            B3s[bc + 2][br]  = f2bf(c0.z);  B3s[bc + 3][br]  = f2bf(c0.w);
            B3s[bc + 4][br]  = f2bf(c1.x);  B3s[bc + 5][br]  = f2bf(c1.y);
            B3s[bc + 6][br]  = f2bf(c1.z);  B3s[bc + 7][br]  = f2bf(c1.w);
            B3s[bc + 8][br]  = f2bf(c2.x);  B3s[bc + 9][br]  = f2bf(c2.y);
            B3s[bc + 10][br] = f2bf(c2.z);  B3s[bc + 11][br] = f2bf(c2.w);
            B3s[bc + 12][br] = f2bf(c3.x);  B3s[bc + 13][br] = f2bf(c3.y);
            B3s[bc + 14][br] = f2bf(c3.z);  B3s[bc + 15][br] = f2bf(c3.w);
        }
        __syncthreads();
        // ---- MFMA compute ----
        s16x8 af[4];
#pragma unroll
        for (int i = 0; i < 4; i++)
            af[i] = *reinterpret_cast<const s16x8*>(&As[wm + i * 16 + l15][quad * 8]);
#pragma unroll
        for (int j = 0; j < 4; j++) {
            s16x8 bf1 = *reinterpret_cast<const s16x8*>(&B1s[wn + j * 16 + l15][quad * 8]);
            s16x8 bf3 = *reinterpret_cast<const s16x8*>(&B3s[wn + j * 16 + l15][quad * 8]);
#pragma unroll
            for (int i = 0; i < 4; i++) {
                acc1[i][j] = __builtin_amdgcn_mfma_f32_16x16x32_bf16(af[i], bf1, acc1[i][j], 0, 0, 0);
                acc3[i][j] = __builtin_amdgcn_mfma_f32_16x16x32_bf16(af[i], bf3, acc3[i][j], 0, 0, 0);
            }
        }
        __syncthreads();
    }

    // ---- epilogue: silu(acc1) * acc3 -> hidden (bf16) ----
#pragma unroll
    for (int i = 0; i < 4; i++) {
#pragma unroll
        for (int j = 0; j < 4; j++) {
            int col = n0 + wn + j * 16 + l15;
#pragma unroll
            for (int r = 0; r < 4; r++) {
                int row = wm + i * 16 + quad * 4 + r;
                int p = m0 + row;
                if (p < cnt) {
                    float z1 = acc1[i][j][r];
                    float z3 = acc3[i][j][r];
                    float hv = (z1 / (1.f + __expf(-z1))) * z3;
                    hidden[(size_t)(base + p) * I_DIM + col] = f2bf(hv);
                }
            }
        }
    }
}

// ---------------- GEMM2: out[tok] += pw * (hidden @ w2), grouped by expert ----------------
__global__ __launch_bounds__(256, 2)
void gemm2_k(const unsigned short* __restrict__ hidden, const float* __restrict__ w2,
             const int* __restrict__ offsets, const int* __restrict__ perm,
             const float* __restrict__ pw, float* __restrict__ out)
{
    int e = blockIdx.z;
    int base = offsets[e];
    int cnt  = offsets[e + 1] - base;
    int m0 = blockIdx.y * BM;
    if (m0 >= cnt) return;
    int n0 = blockIdx.x * BN;

    __shared__ unsigned short As[BM][LDK];
    __shared__ unsigned short Bs[BN][LDK];

    int t = threadIdx.x;
    int lane = t & 63, wave = t >> 6;
    int wm = (wave >> 1) * 64, wn = (wave & 1) * 64;
    int l15 = lane & 15, quad = lane >> 4;

    int ar = t >> 1, ac = (t & 1) * 16;
    int br = t >> 3, bc = (t & 7) * 16;

    const unsigned short* hrow = nullptr;
    { int p = m0 + ar; if (p < cnt) hrow = hidden + (size_t)(base + p) * I_DIM; }

    const float* w2e = w2 + (size_t)e * I_DIM * H_DIM;

    f32x4 acc[4][4] = {};

    for (int k0 = 0; k0 < I_DIM; k0 += BK) {
        // ---- stage A tile (already bf16: straight 16B copies) ----
        {
            uint4 u0, u1;
            if (hrow) {
                const uint4* s = reinterpret_cast<const uint4*>(hrow + k0 + ac);
                u0 = s[0]; u1 = s[1];
            } else {
                u0 = make_uint4(0, 0, 0, 0); u1 = make_uint4(0, 0, 0, 0);
            }
            *reinterpret_cast<uint4*>(&As[ar][ac])     = u0;
            *reinterpret_cast<uint4*>(&As[ar][ac + 8]) = u1;
        }
        // ---- stage B tile (fp32 -> bf16, transposed) ----
        {
            const float4* s = reinterpret_cast<const float4*>(
                w2e + (size_t)(k0 + br) * H_DIM + n0 + bc);
            float4 b0 = s[0], b1 = s[1], b2 = s[2], b3 = s[3];
            Bs[bc + 0][br]  = f2bf(b0.x);  Bs[bc + 1][br]  = f2bf(b0.y);
            Bs[bc + 2][br]  = f2bf(b0.z);  Bs[bc + 3][br]  = f2bf(b0.w);
            Bs[bc + 4][br]  = f2bf(b1.x);  Bs[bc + 5][br]  = f2bf(b1.y);
            Bs[bc + 6][br]  = f2bf(b1.z);  Bs[bc + 7][br]  = f2bf(b1.w);
            Bs[bc + 8][br]  = f2bf(b2.x);  Bs[bc + 9][br]  = f2bf(b2.y);
            Bs[bc + 10][br] = f2bf(b2.z);  Bs[bc + 11][br] = f2bf(b2.w);
            Bs[bc + 12][br] = f2bf(b3.x);  Bs[bc + 13][br] = f2bf(b3.y);
            Bs[bc + 14][br] = f2bf(b3.z);  Bs[bc + 15][br] = f2bf(b3.w);
        }
        __syncthreads();
        s16x8 af[4];
#pragma unroll
        for (int i = 0; i < 4; i++)
            af[i] = *reinterpret_cast<const s16x8*>(&As[wm + i * 16 + l15][quad * 8]);
#pragma unroll
        for (int j = 0; j < 4; j++) {
            s16x8 bfv = *reinterpret_cast<const s16x8*>(&Bs[wn + j * 16 + l15][quad * 8]);
#pragma unroll
            for (int i = 0; i < 4; i++) {
                acc[i][j] = __builtin_amdgcn_mfma_f32_16x16x32_bf16(af[i], bfv, acc[i][j], 0, 0, 0);
            }
        }
        __syncthreads();
    }

    // ---- epilogue: weighted atomic combine into out ----
#pragma unroll
    for (int i = 0; i < 4; i++) {
#pragma unroll
        for (int r = 0; r < 4; r++) {
            int row = wm + i * 16 + quad * 4 + r;
            int p = m0 + row;
            if (p < cnt) {
                int tok = perm[base + p];
                float wgt = pw[base + p];
                float* orow = out + (size_t)tok * H_DIM + n0 + wn;
#pragma unroll
                for (int j = 0; j < 4; j++) {
                    atomicAdd(orow + j * 16 + l15, wgt * acc[i][j][r]);
                }
            }
        }
    }
}

// ---------------- launch ----------------
extern "C" void kernel_launch(void* const* d_in, const int* in_sizes, int n_in,
                              void* d_out, int out_size, void* d_ws, size_t ws_size,
                              hipStream_t stream)
{
    (void)in_sizes; (void)n_in; (void)ws_size;
    const float* x    = (const float*)d_in[0];   // [T, H]
    const float* gw   = (const float*)d_in[1];   // [E, H]
    const float* w1   = (const float*)d_in[2];   // [E, H, I]
    const float* w3   = (const float*)d_in[3];   // [E, H, I]
    const float* w2   = (const float*)d_in[4];   // [E, I, H]
    float* out = (float*)d_out;

    // workspace layout
    char* ws = (char*)d_ws;
    int*   counts  = (int*)ws;                    // 8
    int*   offsets = counts + 8;                  // 9
    int*   cursor  = offsets + 9;                 // 8
    int*   tk_idx  = (int*)(ws + 128);                        // [T*2]
    float* tk_w    = (float*)(ws + 128 + 1 * 131072);         // [T*2]
    int*   perm    = (int*)(ws + 128 + 2 * 131072);           // [TOTP]
    float* pw      = (float*)(ws + 128 + 3 * 131072);         // [TOTP]
    unsigned short* hidden = (unsigned short*)(ws + 524544);  // [TOTP, I] bf16, ~224 MiB

    hipMemsetAsync(ws, 0, 128, stream);                          // zero counts/cursor
    router_k<<<T_TOK, 64, 0, stream>>>(x, gw, tk_idx, tk_w, counts);
    offsets_k<<<1, 64, 0, stream>>>(counts, offsets, cursor);
    scatter_k<<<T_TOK / 256, 256, 0, stream>>>(tk_idx, tk_w, cursor, perm, pw);
    gemm1_k<<<dim3(I_DIM / BN, 128, E_NUM), 256, 0, stream>>>(x, w1, w3, offsets, perm, hidden);
    hipMemsetAsync(out, 0, (size_t)out_size * sizeof(float), stream);
    gemm2_k<<<dim3(H_DIM / BN, 128, E_NUM), 256, 0, stream>>>(hidden, w2, offsets, perm, pw, out);
}

// Round 2
// 1915.229 us; speedup vs baseline: 1.4128x; 1.4128x over previous
//
#include <hip/hip_runtime.h>
#include <hip/hip_bf16.h>

// Problem constants (B=4, S=4096 -> T=16384 tokens)
#define T_TOK 16384
#define H_DIM 1024
#define I_DIM 3584
#define E_NUM 8
#define TOTP  32768   // T_TOK * K(=2)

typedef __attribute__((ext_vector_type(8))) short s16x8;   // 8 bf16 (4 VGPRs) MFMA A/B frag
typedef __attribute__((ext_vector_type(4))) float f32x4;   // MFMA C/D frag
typedef unsigned short u16;

__device__ __forceinline__ u16 f2bf(float f) {
    union { float f; unsigned u; } c; c.f = f;
    unsigned r = c.u + 0x7fffu + ((c.u >> 16) & 1u);   // round-to-nearest-even
    return (u16)(r >> 16);
}

// async global->LDS, 16B per lane. LDS dest must be wave-uniform base + lane*16.
__device__ __forceinline__ void glds16(const u16* g, u16* l) {
    __builtin_amdgcn_global_load_lds(
        (const __attribute__((address_space(1))) unsigned int*)g,
        (__attribute__((address_space(3))) unsigned int*)l,
        16, 0, 0);
}

// ---------------- Router: fp32 logits, top-2, renormalized weights ----------------
__global__ __launch_bounds__(64)
void router_k(const float* __restrict__ x, const float* __restrict__ gw,
              int* __restrict__ tk_idx, float* __restrict__ tk_w,
              int* __restrict__ counts)
{
    int t = blockIdx.x;
    int lane = threadIdx.x;
    const float* xr = x + (size_t)t * H_DIM;
    float xv[16];
#pragma unroll
    for (int j = 0; j < 16; j++) xv[j] = xr[j * 64 + lane];
    float lg[E_NUM];
#pragma unroll
    for (int e = 0; e < E_NUM; e++) {
        const float* g = gw + e * H_DIM;
        float s = 0.f;
#pragma unroll
        for (int j = 0; j < 16; j++) s += xv[j] * g[j * 64 + lane];
#pragma unroll
        for (int off = 32; off > 0; off >>= 1) s += __shfl_xor(s, off, 64);
        lg[e] = s;
    }
    if (lane == 0) {
        int i1 = 0; float m1 = lg[0];
#pragma unroll
        for (int e = 1; e < E_NUM; e++) if (lg[e] > m1) { m1 = lg[e]; i1 = e; }
        int i2 = -1; float m2 = -3.4e38f;
#pragma unroll
        for (int e = 0; e < E_NUM; e++) if (e != i1 && lg[e] > m2) { m2 = lg[e]; i2 = e; }
        float p1 = 1.f / (1.f + __expf(m2 - m1));   // renormalized top-2: denom cancels
        float p2 = 1.f - p1;
        tk_idx[t * 2]     = i1;
        tk_idx[t * 2 + 1] = i2;
        tk_w[t * 2]       = p1;
        tk_w[t * 2 + 1]   = p2;
        atomicAdd(&counts[i1], 1);
        atomicAdd(&counts[i2], 1);
    }
}

__global__ void offsets_k(const int* __restrict__ counts, int* __restrict__ offsets,
                          int* __restrict__ cursor)
{
    if (threadIdx.x == 0 && blockIdx.x == 0) {
        int acc = 0;
        for (int e = 0; e < E_NUM; e++) { offsets[e] = acc; cursor[e] = acc; acc += counts[e]; }
        offsets[E_NUM] = acc;
    }
}

__global__ __launch_bounds__(256)
void scatter_k(const int* __restrict__ tk_idx, const float* __restrict__ tk_w,
               int* __restrict__ cursor, int* __restrict__ perm, float* __restrict__ pw)
{
    int t = blockIdx.x * 256 + threadIdx.x;
    if (t >= T_TOK) return;
#pragma unroll
    for (int k = 0; k < 2; k++) {
        int e = tk_idx[t * 2 + k];
        int pos = atomicAdd(&cursor[e], 1);
        perm[pos] = t;
        pw[pos]   = tk_w[t * 2 + k];
    }
}

// ---------------- x fp32 -> bf16 ----------------
__global__ __launch_bounds__(256)
void cvt_x_k(const float* __restrict__ x, u16* __restrict__ xb)
{
    size_t i = ((size_t)blockIdx.x * 256 + threadIdx.x) * 8;
    float4 a = *reinterpret_cast<const float4*>(x + i);
    float4 b = *reinterpret_cast<const float4*>(x + i + 4);
    union { u16 s[8]; uint4 v; } u;
    u.s[0] = f2bf(a.x); u.s[1] = f2bf(a.y); u.s[2] = f2bf(a.z); u.s[3] = f2bf(a.w);
    u.s[4] = f2bf(b.x); u.s[5] = f2bf(b.y); u.s[6] = f2bf(b.z); u.s[7] = f2bf(b.w);
    *reinterpret_cast<uint4*>(xb + i) = u.v;
}

// ---------------- transpose-convert: src [E][M][N] fp32 -> dst [E][N][M] bf16 ----------------
__global__ __launch_bounds__(256)
void tcvt_k(const float* __restrict__ src, u16* __restrict__ dst, int M, int N)
{
    size_t eo = (size_t)blockIdx.z * M * N;
    __shared__ u16 tl[32][33];
    int t = threadIdx.x;
    int r = t >> 3, c = (t & 7) * 4;
    int m0 = blockIdx.y * 32, n0 = blockIdx.x * 32;
    float4 v = *reinterpret_cast<const float4*>(src + eo + (size_t)(m0 + r) * N + n0 + c);
    tl[c + 0][r] = f2bf(v.x); tl[c + 1][r] = f2bf(v.y);
    tl[c + 2][r] = f2bf(v.z); tl[c + 3][r] = f2bf(v.w);
    __syncthreads();
    union { u16 s[4]; unsigned long long v; } u;
    u.s[0] = tl[r][c]; u.s[1] = tl[r][c + 1]; u.s[2] = tl[r][c + 2]; u.s[3] = tl[r][c + 3];
    *reinterpret_cast<unsigned long long*>(dst + eo + (size_t)(n0 + r) * M + m0 + c) = u.v;
}

// ---------------- GEMM1: hidden = silu(x@w1) * (x@w3), grouped by expert ----------------
// A: gathered xb rows [cnt, H]. B: w1t/w3t [I, H] bf16 (pre-transposed -> [n][k] rows contiguous).
// Tile 128x64xBK32; LDS unpadded row-major, staged via global_load_lds width 16.
__global__ __launch_bounds__(256, 2)
void gemm1_k(const u16* __restrict__ xb, const u16* __restrict__ w1t,
             const u16* __restrict__ w3t, const int* __restrict__ offsets,
             const int* __restrict__ perm, u16* __restrict__ hidden)
{
    int e = blockIdx.z;
    int base = offsets[e];
    int cnt  = offsets[e + 1] - base;
    int m0 = blockIdx.y * 128;
    if (m0 >= cnt) return;
    int n0 = blockIdx.x * 64;

    __shared__ u16 As[128 * 32];   // 8 KB
    __shared__ u16 B1s[64 * 32];   // 4 KB
    __shared__ u16 B3s[64 * 32];   // 4 KB

    int t = threadIdx.x;
    int lane = t & 63, wave = t >> 6;
    int wm = (wave >> 1) * 64, wn = (wave & 1) * 32;
    int l15 = lane & 15, quad = lane >> 4;

    int sr = t >> 2;           // staging row 0..63
    int sc = (t & 3) * 8;      // staging col {0,8,16,24}
    int p0 = m0 + sr;      if (p0 > cnt - 1) p0 = cnt - 1;   // clamp: dup valid row, discarded at epilogue
    int p1 = m0 + 64 + sr; if (p1 > cnt - 1) p1 = cnt - 1;
    const u16* a0p = xb + (size_t)perm[base + p0] * H_DIM + sc;
    const u16* a1p = xb + (size_t)perm[base + p1] * H_DIM + sc;
    const u16* b1p = w1t + (size_t)e * I_DIM * H_DIM + (size_t)(n0 + sr) * H_DIM + sc;
    const u16* b3p = w3t + (size_t)e * I_DIM * H_DIM + (size_t)(n0 + sr) * H_DIM + sc;

    u16* As0 = As + t * 8;             // == wave base + lane*16B
    u16* As1 = As + 2048 + t * 8;
    u16* B1d = B1s + t * 8;
    u16* B3d = B3s + t * 8;

    f32x4 acc1[4][2] = {};
    f32x4 acc3[4][2] = {};

    for (int k0 = 0; k0 < H_DIM; k0 += 32) {
        glds16(a0p + k0, As0);
        glds16(a1p + k0, As1);
        glds16(b1p + k0, B1d);
        glds16(b3p + k0, B3d);
        __syncthreads();   // drains vmcnt (glds) per barrier semantics
        s16x8 af[4];
#pragma unroll
        for (int i = 0; i < 4; i++)
            af[i] = *reinterpret_cast<const s16x8*>(As + (wm + i * 16 + l15) * 32 + quad * 8);
#pragma unroll
        for (int j = 0; j < 2; j++) {
            s16x8 b1 = *reinterpret_cast<const s16x8*>(B1s + (wn + j * 16 + l15) * 32 + quad * 8);
            s16x8 b3 = *reinterpret_cast<const s16x8*>(B3s + (wn + j * 16 + l15) * 32 + quad * 8);
#pragma unroll
            for (int i = 0; i < 4; i++) {
                acc1[i][j] = __builtin_amdgcn_mfma_f32_16x16x32_bf16(af[i], b1, acc1[i][j], 0, 0, 0);
                acc3[i][j] = __builtin_amdgcn_mfma_f32_16x16x32_bf16(af[i], b3, acc3[i][j], 0, 0, 0);
            }
        }
        __syncthreads();
    }

    // epilogue: silu(acc1) * acc3 -> hidden bf16
#pragma unroll
    for (int i = 0; i < 4; i++) {
#pragma unroll
        for (int j = 0; j < 2; j++) {
            int col = n0 + wn + j * 16 + l15;
#pragma unroll
            for (int r = 0; r < 4; r++) {
                int p = m0 + wm + i * 16 + quad * 4 + r;
                if (p < cnt) {
                    float z1 = acc1[i][j][r];
                    float z3 = acc3[i][j][r];
                    float hv = (z1 / (1.f + __expf(-z1))) * z3;
                    hidden[(size_t)(base + p) * I_DIM + col] = f2bf(hv);
                }
            }
        }
    }
}

// ---------------- GEMM2: out[tok] += pw * (hidden @ w2), grouped by expert ----------------
// A: hidden rows (already grouped, bf16). B: w2t [H, I] bf16 (pre-transposed).
__global__ __launch_bounds__(256, 2)
void gemm2_k(const u16* __restrict__ hidden, const u16* __restrict__ w2t,
             const int* __restrict__ offsets, const int* __restrict__ perm,
             const float* __restrict__ pw, float* __restrict__ out)
{
    int e = blockIdx.z;
    int base = offsets[e];
    int cnt  = offsets[e + 1] - base;
    int m0 = blockIdx.y * 128;
    if (m0 >= cnt) return;
    int n0 = blockIdx.x * 128;

    __shared__ u16 As[128 * 32];   // 8 KB
    __shared__ u16 Bs[128 * 32];   // 8 KB

    int t = threadIdx.x;
    int lane = t & 63, wave = t >> 6;
    int wm = (wave >> 1) * 64, wn = (wave & 1) * 64;
    int l15 = lane & 15, quad = lane >> 4;

    int sr = t >> 2;
    int sc = (t & 3) * 8;
    int p0 = m0 + sr;      if (p0 > cnt - 1) p0 = cnt - 1;
    int p1 = m0 + 64 + sr; if (p1 > cnt - 1) p1 = cnt - 1;
    const u16* a0p = hidden + (size_t)(base + p0) * I_DIM + sc;
    const u16* a1p = hidden + (size_t)(base + p1) * I_DIM + sc;
    const u16* wb  = w2t + (size_t)e * H_DIM * I_DIM;
    const u16* b0p = wb + (size_t)(n0 + sr) * I_DIM + sc;
    const u16* b1p = wb + (size_t)(n0 + 64 + sr) * I_DIM + sc;

    u16* As0 = As + t * 8;
    u16* As1 = As + 2048 + t * 8;
    u16* Bs0 = Bs + t * 8;
    u16* Bs1 = Bs + 2048 + t * 8;

    f32x4 acc[4][4] = {};

    for (int k0 = 0; k0 < I_DIM; k0 += 32) {
        glds16(a0p + k0, As0);
        glds16(a1p + k0, As1);
        glds16(b0p + k0, Bs0);
        glds16(b1p + k0, Bs1);
        __syncthreads();
        s16x8 af[4];
#pragma unroll
        for (int i = 0; i < 4; i++)
            af[i] = *reinterpret_cast<const s16x8*>(As + (wm + i * 16 + l15) * 32 + quad * 8);
#pragma unroll
        for (int j = 0; j < 4; j++) {
            s16x8 bfv = *reinterpret_cast<const s16x8*>(Bs + (wn + j * 16 + l15) * 32 + quad * 8);
#pragma unroll
            for (int i = 0; i < 4; i++)
                acc[i][j] = __builtin_amdgcn_mfma_f32_16x16x32_bf16(af[i], bfv, acc[i][j], 0, 0, 0);
        }
        __syncthreads();
    }

    // epilogue: weighted atomic combine (each out element receives exactly 2 adds)
#pragma unroll
    for (int i = 0; i < 4; i++) {
#pragma unroll
        for (int r = 0; r < 4; r++) {
            int p = m0 + wm + i * 16 + quad * 4 + r;
            if (p < cnt) {
                int tok = perm[base + p];
                float wgt = pw[base + p];
                float* orow = out + (size_t)tok * H_DIM + n0 + wn;
#pragma unroll
                for (int j = 0; j < 4; j++)
                    atomicAdd(orow + j * 16 + l15, wgt * acc[i][j][r]);
            }
        }
    }
}

// ---------------- launch ----------------
extern "C" void kernel_launch(void* const* d_in, const int* in_sizes, int n_in,
                              void* d_out, int out_size, void* d_ws, size_t ws_size,
                              hipStream_t stream)
{
    (void)in_sizes; (void)n_in; (void)ws_size;
    const float* x  = (const float*)d_in[0];   // [T, H]
    const float* gw = (const float*)d_in[1];   // [E, H]
    const float* w1 = (const float*)d_in[2];   // [E, H, I]
    const float* w3 = (const float*)d_in[3];   // [E, H, I]
    const float* w2 = (const float*)d_in[4];   // [E, I, H]
    float* out = (float*)d_out;

    char* ws = (char*)d_ws;
    int*   counts  = (int*)ws;
    int*   offsets = counts + 8;
    int*   cursor  = offsets + 9;
    int*   tk_idx  = (int*)(ws + 128);
    float* tk_w    = (float*)(ws + 128 + 131072);
    int*   perm    = (int*)(ws + 128 + 2 * 131072);
    float* pw      = (float*)(ws + 128 + 3 * 131072);
    u16* xb     = (u16*)(ws + (1 << 20));                       // 33.5 MB
    u16* w1t    = xb + 16777216ull;                             // [E,I,H] bf16, 58.7 MB
    u16* w3t    = w1t + 29360128ull;                            // 58.7 MB
    u16* w2t    = w3t + 29360128ull;                            // [E,H,I] bf16, 58.7 MB
    u16* hidden = w2t + 29360128ull;                            // [TOTP, I] bf16, 234.9 MB

    hipMemsetAsync(ws, 0, 128, stream);
    router_k<<<T_TOK, 64, 0, stream>>>(x, gw, tk_idx, tk_w, counts);
    offsets_k<<<1, 64, 0, stream>>>(counts, offsets, cursor);
    scatter_k<<<T_TOK / 256, 256, 0, stream>>>(tk_idx, tk_w, cursor, perm, pw);
    cvt_x_k<<<8192, 256, 0, stream>>>(x, xb);
    tcvt_k<<<dim3(I_DIM / 32, H_DIM / 32, E_NUM), 256, 0, stream>>>(w1, w1t, H_DIM, I_DIM);
    tcvt_k<<<dim3(I_DIM / 32, H_DIM / 32, E_NUM), 256, 0, stream>>>(w3, w3t, H_DIM, I_DIM);
    tcvt_k<<<dim3(H_DIM / 32, I_DIM / 32, E_NUM), 256, 0, stream>>>(w2, w2t, I_DIM, H_DIM);
    gemm1_k<<<dim3(I_DIM / 64, 128, E_NUM), 256, 0, stream>>>(xb, w1t, w3t, offsets, perm, hidden);
    hipMemsetAsync(out, 0, (size_t)out_size * sizeof(float), stream);
    gemm2_k<<<dim3(H_DIM / 128, 128, E_NUM), 256, 0, stream>>>(hidden, w2t, offsets, perm, pw, out);
}

// Round 3
// 1868.531 us; speedup vs baseline: 1.4481x; 1.0250x over previous
//
#include <hip/hip_runtime.h>
#include <hip/hip_bf16.h>

// Problem constants (B=4, S=4096 -> T=16384 tokens)
#define T_TOK 16384
#define H_DIM 1024
#define I_DIM 3584
#define E_NUM 8
#define TOTP  32768   // T_TOK * K(=2)

typedef __attribute__((ext_vector_type(8))) short s16x8;   // 8 bf16 (4 VGPRs) MFMA A/B frag
typedef __attribute__((ext_vector_type(4))) float f32x4;   // MFMA C/D frag
typedef unsigned short u16;

__device__ __forceinline__ u16 f2bf(float f) {
    union { float f; unsigned u; } c; c.f = f;
    unsigned r = c.u + 0x7fffu + ((c.u >> 16) & 1u);   // round-to-nearest-even
    return (u16)(r >> 16);
}

// async global->LDS, 16B per lane. LDS dest must be wave-uniform base + lane*16.
__device__ __forceinline__ void glds16(const u16* g, u16* l) {
    __builtin_amdgcn_global_load_lds(
        (const __attribute__((address_space(1))) unsigned int*)g,
        (__attribute__((address_space(3))) unsigned int*)l,
        16, 0, 0);
}

// ---------------- Router: fp32 logits, top-2, renorm weights; also emits x in bf16 ----------------
__global__ __launch_bounds__(64)
void router_k(const float* __restrict__ x, const float* __restrict__ gw,
              int* __restrict__ tk_idx, float* __restrict__ tk_w,
              int* __restrict__ counts, u16* __restrict__ xb)
{
    int t = blockIdx.x;
    int lane = threadIdx.x;
    const float* xr = x + (size_t)t * H_DIM;
    float xv[16];
#pragma unroll
    for (int j = 0; j < 16; j++) xv[j] = xr[j * 64 + lane];
    // fused x -> bf16
    u16* xo = xb + (size_t)t * H_DIM;
#pragma unroll
    for (int j = 0; j < 16; j++) xo[j * 64 + lane] = f2bf(xv[j]);
    float lg[E_NUM];
#pragma unroll
    for (int e = 0; e < E_NUM; e++) {
        const float* g = gw + e * H_DIM;
        float s = 0.f;
#pragma unroll
        for (int j = 0; j < 16; j++) s += xv[j] * g[j * 64 + lane];
#pragma unroll
        for (int off = 32; off > 0; off >>= 1) s += __shfl_xor(s, off, 64);
        lg[e] = s;
    }
    if (lane == 0) {
        int i1 = 0; float m1 = lg[0];
#pragma unroll
        for (int e = 1; e < E_NUM; e++) if (lg[e] > m1) { m1 = lg[e]; i1 = e; }
        int i2 = -1; float m2 = -3.4e38f;
#pragma unroll
        for (int e = 0; e < E_NUM; e++) if (e != i1 && lg[e] > m2) { m2 = lg[e]; i2 = e; }
        float p1 = 1.f / (1.f + __expf(m2 - m1));   // renormalized top-2: denom cancels
        float p2 = 1.f - p1;
        tk_idx[t * 2]     = i1;
        tk_idx[t * 2 + 1] = i2;
        tk_w[t * 2]       = p1;
        tk_w[t * 2 + 1]   = p2;
        atomicAdd(&counts[i1], 1);
        atomicAdd(&counts[i2], 1);
    }
}

__global__ void offsets_k(const int* __restrict__ counts, int* __restrict__ offsets,
                          int* __restrict__ cursor)
{
    if (threadIdx.x == 0 && blockIdx.x == 0) {
        int acc = 0;
        for (int e = 0; e < E_NUM; e++) { offsets[e] = acc; cursor[e] = acc; acc += counts[e]; }
        offsets[E_NUM] = acc;
    }
}

__global__ __launch_bounds__(256)
void scatter_k(const int* __restrict__ tk_idx, const float* __restrict__ tk_w,
               int* __restrict__ cursor, int* __restrict__ perm, float* __restrict__ pw,
               int* __restrict__ posmap)
{
    int t = blockIdx.x * 256 + threadIdx.x;
    if (t >= T_TOK) return;
#pragma unroll
    for (int k = 0; k < 2; k++) {
        int e = tk_idx[t * 2 + k];
        int pos = atomicAdd(&cursor[e], 1);
        perm[pos] = t;
        pw[pos]   = tk_w[t * 2 + k];
        posmap[t * 2 + k] = pos;
    }
}

// ---------------- transpose-convert: src [E][M][N] fp32 -> dst [E][N][M] bf16 ----------------
__global__ __launch_bounds__(256)
void tcvt_k(const float* __restrict__ src, u16* __restrict__ dst, int M, int N)
{
    size_t eo = (size_t)blockIdx.z * M * N;
    __shared__ u16 tl[32][33];
    int t = threadIdx.x;
    int r = t >> 3, c = (t & 7) * 4;
    int m0 = blockIdx.y * 32, n0 = blockIdx.x * 32;
    float4 v = *reinterpret_cast<const float4*>(src + eo + (size_t)(m0 + r) * N + n0 + c);
    tl[c + 0][r] = f2bf(v.x); tl[c + 1][r] = f2bf(v.y);
    tl[c + 2][r] = f2bf(v.z); tl[c + 3][r] = f2bf(v.w);
    __syncthreads();
    union { u16 s[4]; unsigned long long v; } u;
    u.s[0] = tl[r][c]; u.s[1] = tl[r][c + 1]; u.s[2] = tl[r][c + 2]; u.s[3] = tl[r][c + 3];
    *reinterpret_cast<unsigned long long*>(dst + eo + (size_t)(n0 + r) * M + m0 + c) = u.v;
}

// ---------------- GEMM1: hidden = pw * silu(x@w1) * (x@w3), grouped by expert ----------------
// A: gathered xb rows [cnt, H]. B: w1t/w3t [I, H] bf16 (pre-transposed -> [n][k] rows contiguous).
// Tile 128x64xBK32; LDS unpadded row-major, staged via global_load_lds width 16.
__global__ __launch_bounds__(256, 2)
void gemm1_k(const u16* __restrict__ xb, const u16* __restrict__ w1t,
             const u16* __restrict__ w3t, const int* __restrict__ offsets,
             const int* __restrict__ perm, const float* __restrict__ pw,
             u16* __restrict__ hidden)
{
    int e = blockIdx.z;
    int base = offsets[e];
    int cnt  = offsets[e + 1] - base;
    int m0 = blockIdx.y * 128;
    if (m0 >= cnt) return;
    int n0 = blockIdx.x * 64;

    __shared__ u16 As[128 * 32];   // 8 KB
    __shared__ u16 B1s[64 * 32];   // 4 KB
    __shared__ u16 B3s[64 * 32];   // 4 KB

    int t = threadIdx.x;
    int lane = t & 63, wave = t >> 6;
    int wm = (wave >> 1) * 64, wn = (wave & 1) * 32;
    int l15 = lane & 15, quad = lane >> 4;

    int sr = t >> 2;           // staging row 0..63
    int sc = (t & 3) * 8;      // staging col {0,8,16,24}
    int p0 = m0 + sr;      if (p0 > cnt - 1) p0 = cnt - 1;   // clamp: dup valid row, discarded at epilogue
    int p1 = m0 + 64 + sr; if (p1 > cnt - 1) p1 = cnt - 1;
    const u16* a0p = xb + (size_t)perm[base + p0] * H_DIM + sc;
    const u16* a1p = xb + (size_t)perm[base + p1] * H_DIM + sc;
    const u16* b1p = w1t + (size_t)e * I_DIM * H_DIM + (size_t)(n0 + sr) * H_DIM + sc;
    const u16* b3p = w3t + (size_t)e * I_DIM * H_DIM + (size_t)(n0 + sr) * H_DIM + sc;

    u16* As0 = As + t * 8;             // == wave base + lane*16B
    u16* As1 = As + 2048 + t * 8;
    u16* B1d = B1s + t * 8;
    u16* B3d = B3s + t * 8;

    f32x4 acc1[4][2] = {};
    f32x4 acc3[4][2] = {};

    for (int k0 = 0; k0 < H_DIM; k0 += 32) {
        glds16(a0p + k0, As0);
        glds16(a1p + k0, As1);
        glds16(b1p + k0, B1d);
        glds16(b3p + k0, B3d);
        __syncthreads();   // drains vmcnt (glds) per barrier semantics
        s16x8 af[4];
#pragma unroll
        for (int i = 0; i < 4; i++)
            af[i] = *reinterpret_cast<const s16x8*>(As + (wm + i * 16 + l15) * 32 + quad * 8);
#pragma unroll
        for (int j = 0; j < 2; j++) {
            s16x8 b1 = *reinterpret_cast<const s16x8*>(B1s + (wn + j * 16 + l15) * 32 + quad * 8);
            s16x8 b3 = *reinterpret_cast<const s16x8*>(B3s + (wn + j * 16 + l15) * 32 + quad * 8);
#pragma unroll
            for (int i = 0; i < 4; i++) {
                acc1[i][j] = __builtin_amdgcn_mfma_f32_16x16x32_bf16(af[i], b1, acc1[i][j], 0, 0, 0);
                acc3[i][j] = __builtin_amdgcn_mfma_f32_16x16x32_bf16(af[i], b3, acc3[i][j], 0, 0, 0);
            }
        }
        __syncthreads();
    }

    // epilogue: pw * silu(acc1) * acc3 -> hidden bf16 (routing weight folded in here)
#pragma unroll
    for (int i = 0; i < 4; i++) {
#pragma unroll
        for (int j = 0; j < 2; j++) {
            int col = n0 + wn + j * 16 + l15;
#pragma unroll
            for (int r = 0; r < 4; r++) {
                int p = m0 + wm + i * 16 + quad * 4 + r;
                if (p < cnt) {
                    float z1 = acc1[i][j][r];
                    float z3 = acc3[i][j][r];
                    float hv = (z1 / (1.f + __expf(-z1))) * z3 * pw[base + p];
                    hidden[(size_t)(base + p) * I_DIM + col] = f2bf(hv);
                }
            }
        }
    }
}

// ---------------- GEMM2: ybuf[pos] = hidden[pos] @ w2  (plain stores, no atomics) ----------------
__global__ __launch_bounds__(256, 2)
void gemm2_k(const u16* __restrict__ hidden, const u16* __restrict__ w2t,
             const int* __restrict__ offsets, float* __restrict__ ybuf)
{
    int e = blockIdx.z;
    int base = offsets[e];
    int cnt  = offsets[e + 1] - base;
    int m0 = blockIdx.y * 128;
    if (m0 >= cnt) return;
    int n0 = blockIdx.x * 128;

    __shared__ u16 As[128 * 32];   // 8 KB
    __shared__ u16 Bs[128 * 32];   // 8 KB

    int t = threadIdx.x;
    int lane = t & 63, wave = t >> 6;
    int wm = (wave >> 1) * 64, wn = (wave & 1) * 64;
    int l15 = lane & 15, quad = lane >> 4;

    int sr = t >> 2;
    int sc = (t & 3) * 8;
    int p0 = m0 + sr;      if (p0 > cnt - 1) p0 = cnt - 1;
    int p1 = m0 + 64 + sr; if (p1 > cnt - 1) p1 = cnt - 1;
    const u16* a0p = hidden + (size_t)(base + p0) * I_DIM + sc;
    const u16* a1p = hidden + (size_t)(base + p1) * I_DIM + sc;
    const u16* wb  = w2t + (size_t)e * H_DIM * I_DIM;
    const u16* b0p = wb + (size_t)(n0 + sr) * I_DIM + sc;
    const u16* b1p = wb + (size_t)(n0 + 64 + sr) * I_DIM + sc;

    u16* As0 = As + t * 8;
    u16* As1 = As + 2048 + t * 8;
    u16* Bs0 = Bs + t * 8;
    u16* Bs1 = Bs + 2048 + t * 8;

    f32x4 acc[4][4] = {};

    for (int k0 = 0; k0 < I_DIM; k0 += 32) {
        glds16(a0p + k0, As0);
        glds16(a1p + k0, As1);
        glds16(b0p + k0, Bs0);
        glds16(b1p + k0, Bs1);
        __syncthreads();
        s16x8 af[4];
#pragma unroll
        for (int i = 0; i < 4; i++)
            af[i] = *reinterpret_cast<const s16x8*>(As + (wm + i * 16 + l15) * 32 + quad * 8);
#pragma unroll
        for (int j = 0; j < 4; j++) {
            s16x8 bfv = *reinterpret_cast<const s16x8*>(Bs + (wn + j * 16 + l15) * 32 + quad * 8);
#pragma unroll
            for (int i = 0; i < 4; i++)
                acc[i][j] = __builtin_amdgcn_mfma_f32_16x16x32_bf16(af[i], bfv, acc[i][j], 0, 0, 0);
        }
        __syncthreads();
    }

    // epilogue: plain stores to grouped ybuf
#pragma unroll
    for (int i = 0; i < 4; i++) {
#pragma unroll
        for (int r = 0; r < 4; r++) {
            int p = m0 + wm + i * 16 + quad * 4 + r;
            if (p < cnt) {
                float* orow = ybuf + (size_t)(base + p) * H_DIM + n0 + wn;
#pragma unroll
                for (int j = 0; j < 4; j++)
                    orow[j * 16 + l15] = acc[i][j][r];
            }
        }
    }
}

// ---------------- Combine: out[t] = ybuf[pos_a] + ybuf[pos_b] ----------------
// One block per token row (256 threads x float4 = 1024 floats).
__global__ __launch_bounds__(256)
void combine_k(const float* __restrict__ ybuf, const int* __restrict__ posmap,
               float* __restrict__ out)
{
    int t = blockIdx.x;
    int c = threadIdx.x * 4;
    int pa = posmap[t * 2];
    int pb = posmap[t * 2 + 1];
    float4 a = *reinterpret_cast<const float4*>(ybuf + (size_t)pa * H_DIM + c);
    float4 b = *reinterpret_cast<const float4*>(ybuf + (size_t)pb * H_DIM + c);
    float4 o = make_float4(a.x + b.x, a.y + b.y, a.z + b.z, a.w + b.w);
    *reinterpret_cast<float4*>(out + (size_t)t * H_DIM + c) = o;
}

// ---------------- launch ----------------
extern "C" void kernel_launch(void* const* d_in, const int* in_sizes, int n_in,
                              void* d_out, int out_size, void* d_ws, size_t ws_size,
                              hipStream_t stream)
{
    (void)in_sizes; (void)n_in; (void)ws_size; (void)out_size;
    const float* x  = (const float*)d_in[0];   // [T, H]
    const float* gw = (const float*)d_in[1];   // [E, H]
    const float* w1 = (const float*)d_in[2];   // [E, H, I]
    const float* w3 = (const float*)d_in[3];   // [E, H, I]
    const float* w2 = (const float*)d_in[4];   // [E, I, H]
    float* out = (float*)d_out;

    char* ws = (char*)d_ws;
    int*   counts  = (int*)ws;
    int*   offsets = counts + 8;
    int*   cursor  = offsets + 9;
    int*   tk_idx  = (int*)(ws + 128);
    float* tk_w    = (float*)(ws + 128 + 131072);
    int*   perm    = (int*)(ws + 128 + 2 * 131072);
    float* pw      = (float*)(ws + 128 + 3 * 131072);
    int*   posmap  = (int*)(ws + 128 + 4 * 131072);
    u16* xb     = (u16*)(ws + (1 << 20));                       // 33.5 MB
    u16* w1t    = xb + 16777216ull;                             // [E,I,H] bf16, 58.7 MB
    u16* w3t    = w1t + 29360128ull;                            // 58.7 MB
    u16* w2t    = w3t + 29360128ull;                            // [E,H,I] bf16, 58.7 MB
    u16* hidden = w2t + 29360128ull;                            // [TOTP, I] bf16, 234.9 MB
    // ybuf (134 MB fp32) aliases xb+w1t+w3t (151 MB) — all dead after gemm1 completes
    float* ybuf = (float*)(ws + (1 << 20));

    hipMemsetAsync(ws, 0, 128, stream);
    router_k<<<T_TOK, 64, 0, stream>>>(x, gw, tk_idx, tk_w, counts, xb);
    offsets_k<<<1, 64, 0, stream>>>(counts, offsets, cursor);
    scatter_k<<<T_TOK / 256, 256, 0, stream>>>(tk_idx, tk_w, cursor, perm, pw, posmap);
    tcvt_k<<<dim3(I_DIM / 32, H_DIM / 32, E_NUM), 256, 0, stream>>>(w1, w1t, H_DIM, I_DIM);
    tcvt_k<<<dim3(I_DIM / 32, H_DIM / 32, E_NUM), 256, 0, stream>>>(w3, w3t, H_DIM, I_DIM);
    tcvt_k<<<dim3(H_DIM / 32, I_DIM / 32, E_NUM), 256, 0, stream>>>(w2, w2t, I_DIM, H_DIM);
    gemm1_k<<<dim3(I_DIM / 64, 128, E_NUM), 256, 0, stream>>>(xb, w1t, w3t, offsets, perm, pw, hidden);
    gemm2_k<<<dim3(H_DIM / 128, 128, E_NUM), 256, 0, stream>>>(hidden, w2t, offsets, ybuf);
    combine_k<<<T_TOK, 256, 0, stream>>>(ybuf, posmap, out);
}